// Round 14
// baseline (195.271 us; speedup 1.0000x reference)
//
#include <hip/hip_runtime.h>
#include <hip/hip_bf16.h>

#define N_NODES 50000
#define E_EDGES 800000
#define D_IN    128
#define ED_IN   32
#define H_HID   16
#define D_CAT   144
#define AGG_LD  144   // aggb row stride; gemm1 overreads 16 into next row, killed by BT zero cols
#define BCAP    48    // bucket capacity per node (P(deg>=48) ~ 5e-5; clamped)
#define BM      64    // rows per block in MFMA GEMM kernels
#define EDGE_BLKS (E_EDGES / 256)   // 3125

typedef __attribute__((ext_vector_type(8))) short bf16x8;   // 8 bf16 = 4 VGPRs
typedef __attribute__((ext_vector_type(4))) float f32x4;

__device__ __forceinline__ float gelu_exact(float v) {
    return 0.5f * v * (1.0f + erff(v * 0.70710678118654752f));
}
__device__ __forceinline__ float4 ld4(const float* p) { return *reinterpret_cast<const float4*>(p); }
__device__ __forceinline__ unsigned short f2bf(float f) {   // RNE bf16 (cold paths only)
    unsigned u = __float_as_uint(f);
    return (unsigned short)((u + 0x7FFFu + ((u >> 16) & 1u)) >> 16);
}
__device__ __forceinline__ float bflo(unsigned u) { return __uint_as_float(u << 16); }
__device__ __forceinline__ float bfhi(unsigned u) { return __uint_as_float(u & 0xffff0000u); }
// hot-path pair conversion -> v_cvt_pk_bf16_f32 (RNE)
__device__ __forceinline__ unsigned packbf2(float lo, float hi) {
    __hip_bfloat162 h = __float22bfloat162_rn(make_float2(lo, hi));
    return *reinterpret_cast<unsigned*>(&h);
}

// zero cnt (12500 int4) + stats (256 f32)
__global__ __launch_bounds__(256) void k_zero(int* __restrict__ cnt, float* __restrict__ stats) {
    int i = blockIdx.x * 256 + threadIdx.x;
    if (i < 12500) *reinterpret_cast<int4*>(cnt + i * 4) = make_int4(0, 0, 0, 0);
    if (blockIdx.x == 49 && threadIdx.x < 64)
        *reinterpret_cast<float4*>(stats + threadIdx.x * 4) = make_float4(0.f, 0.f, 0.f, 0.f);
}

// Fused edge kernel + weight-prep tail blocks.
// blocks 0..3124 (edge): (a) placement: atomic on cnt[dst], 4B bucket store;
//                        (b) g = gelu(ef@eW1+eb1) via MFMA -> gbuf[e] coalesced.
// blocks 3125..3252: BT cols 0:128 = M = (1+eps)*egoW@W1   (d = b-3125)
// block  3253:       BT cols 128:256 = W1[0:128]; 256:272 = W1e; 272:288 = 0; ve
// block  3254:       W2T
__global__ __launch_bounds__(256) void k_edge(const float* __restrict__ x,
        const int* __restrict__ eidx, const float* __restrict__ ef,
        const float* __restrict__ eW1, const float* __restrict__ eb1,
        const float* __restrict__ egoW, const float* __restrict__ W1,
        const float* __restrict__ eps, const float* __restrict__ eW2,
        const float* __restrict__ eb2, const float* __restrict__ W2,
        int* __restrict__ cnt, int* __restrict__ bucket,
        unsigned short* __restrict__ gbuf, unsigned short* __restrict__ BT,
        unsigned short* __restrict__ W2T, float* __restrict__ ve) {
    const int b = blockIdx.x, t = threadIdx.x;
    if (b >= EDGE_BLKS) {                    // ---- prep tail blocks ----
        if (t >= 128) return;
        const int c = t;
        const int d = b - EDGE_BLKS;
        if (d < 128) {
            float acc = 0.f;
            for (int j = 0; j < D_CAT; ++j)
                acc = fmaf(egoW[d * D_CAT + j], W1[j * 128 + c], acc);
            BT[c * 288 + d] = f2bf((1.0f + eps[0]) * acc);
        } else if (d == 128) {
            for (int j = 0; j < 128; ++j)
                BT[c * 288 + 128 + j] = f2bf(W1[j * 128 + c]);
            #pragma unroll
            for (int j = 0; j < H_HID; ++j) {
                float s = 0.f;
                #pragma unroll
                for (int k = 0; k < H_HID; ++k)
                    s = fmaf(eW2[j * H_HID + k], W1[(D_IN + k) * 128 + c], s);
                BT[c * 288 + 256 + j] = f2bf(s);
            }
            #pragma unroll
            for (int j = 272; j < 288; ++j) BT[c * 288 + j] = 0;
            float s = 0.f;
            #pragma unroll
            for (int k = 0; k < H_HID; ++k)
                s = fmaf(eb2[k], W1[(D_IN + k) * 128 + c], s);
            ve[c] = s;
        } else {
            for (int k = 0; k < 128; ++k)
                W2T[c * 128 + k] = f2bf(W2[k * 128 + c]);
        }
        return;
    }
    // ---- edge blocks ----
    const int e0 = b * 256;
    const int i = e0 + t;
    const int w = t >> 6, l = t & 63, q = l >> 4, c = l & 15;
    const int eb = e0 + w * 64;

    // issue phase: all independent global loads
    int dst = eidx[E_EDGES + i];
    float4 ef0[4], ef1[4];
    #pragma unroll
    for (int m = 0; m < 4; ++m) {
        const float* ep = ef + (size_t)(eb + m * 16 + c) * ED_IN + q * 8;
        ef0[m] = ld4(ep);
        ef1[m] = ld4(ep + 4);
    }
    float wv[8];
    #pragma unroll
    for (int j = 0; j < 8; ++j) wv[j] = eW1[(q * 8 + j) * 16 + c];
    union { uint4 u; bf16x8 v; } afc;
    afc.u.x = packbf2(wv[0], wv[1]); afc.u.y = packbf2(wv[2], wv[3]);
    afc.u.z = packbf2(wv[4], wv[5]); afc.u.w = packbf2(wv[6], wv[7]);
    const bf16x8 af = afc.v;                 // A[row=c][k=q*8+j]
    float bias[4];
    #pragma unroll
    for (int j = 0; j < 4; ++j) bias[j] = eb1[q * 4 + j];

    {   // placement
        int pos = atomicAdd(&cnt[dst], 1);
        if (pos < BCAP) bucket[dst * BCAP + pos] = i;
    }
    // g-MFMA: 4 x mfma_16x16x32, coalesced gbuf writes
    #pragma unroll
    for (int m = 0; m < 4; ++m) {
        const int em = eb + m * 16 + c;
        union { uint4 u; bf16x8 v; } bc;
        bc.u.x = packbf2(ef0[m].x, ef0[m].y); bc.u.y = packbf2(ef0[m].z, ef0[m].w);
        bc.u.z = packbf2(ef1[m].x, ef1[m].y); bc.u.w = packbf2(ef1[m].z, ef1[m].w);
        f32x4 acc = (f32x4){0.f, 0.f, 0.f, 0.f};
        acc = __builtin_amdgcn_mfma_f32_16x16x32_bf16(af, bc.v, acc, 0, 0, 0);
        uint2 o;
        o.x = packbf2(gelu_exact(acc[0] + bias[0]), gelu_exact(acc[1] + bias[1]));
        o.y = packbf2(gelu_exact(acc[2] + bias[2]), gelu_exact(acc[3] + bias[3]));
        *reinterpret_cast<uint2*>(gbuf + (size_t)em * 16 + q * 4) = o;
    }
}

// Bucket aggregation -> aggb rows [x(128) | g(16)] bf16, stride 144.
// Gathers f32 x rows directly (32B/lane, L3-resident); g bf16 from gbuf.
__global__ __launch_bounds__(256) void k_agg(const float* __restrict__ x,
        const int* __restrict__ eidx, const int* __restrict__ cnt,
        const int* __restrict__ bucket, const unsigned short* __restrict__ gbuf,
        unsigned short* __restrict__ aggb) {
    const int wave = threadIdx.x >> 6, lane = threadIdx.x & 63;
    const int q = lane >> 4, ql = lane & 15;
    const int n = blockIdx.x * 4 + wave;
    const int m = min(cnt[n], BCAP);
    int ev = (lane < BCAP) ? bucket[n * BCAP + lane] : 0;
    int sv = (lane < m) ? eidx[ev] : 0;             // per-lane src, independent loads
    float a[8], ae[8];
    #pragma unroll
    for (int i = 0; i < 8; ++i) { a[i] = 0.f; ae[i] = 0.f; }
    const int ng = (m + 3) >> 2;
    #pragma unroll 4
    for (int j = 0; j < ng; ++j) {
        const int eo = 4 * j + q;
        const int s  = __shfl(sv, eo);
        const int ge = __shfl(ev, eo);
        if (eo < m) {
            const float* xp = x + (size_t)s * D_IN + ql * 8;
            float4 v0 = ld4(xp), v1 = ld4(xp + 4);
            a[0] += v0.x; a[1] += v0.y; a[2] += v0.z; a[3] += v0.w;
            a[4] += v1.x; a[5] += v1.y; a[6] += v1.z; a[7] += v1.w;
            if (ql < 2) {
                uint4 e = *reinterpret_cast<const uint4*>(gbuf + (size_t)ge * 16 + ql * 8);
                ae[0] += bflo(e.x); ae[1] += bfhi(e.x);
                ae[2] += bflo(e.y); ae[3] += bfhi(e.y);
                ae[4] += bflo(e.z); ae[5] += bfhi(e.z);
                ae[6] += bflo(e.w); ae[7] += bfhi(e.w);
            }
        }
    }
    #pragma unroll
    for (int i = 0; i < 8; ++i) {
        a[i]  += __shfl_xor(a[i], 16);  a[i]  += __shfl_xor(a[i], 32);
        ae[i] += __shfl_xor(ae[i], 16); ae[i] += __shfl_xor(ae[i], 32);
    }
    if (q == 0) {
        unsigned short* ar = aggb + (size_t)n * AGG_LD;
        uint4 o;
        o.x = packbf2(a[0], a[1]); o.y = packbf2(a[2], a[3]);
        o.z = packbf2(a[4], a[5]); o.w = packbf2(a[6], a[7]);
        *reinterpret_cast<uint4*>(ar + ql * 8) = o;
        if (ql < 2) {
            uint4 oe;
            oe.x = packbf2(ae[0], ae[1]); oe.y = packbf2(ae[2], ae[3]);
            oe.z = packbf2(ae[4], ae[5]); oe.w = packbf2(ae[6], ae[7]);
            *reinterpret_cast<uint4*>(ar + D_IN + ql * 8) = oe;
        }
    }
}

// MFMA GEMM1: h[N,128] = [x | aggb] @ BT^T + deg*ve ; col stats
// ch<4 A-tiles read x f32 and convert during staging (cvt_pk).
// A-overread past aggb row end (16 elems of next row) hits BT zero cols 272:288 -> no-op.
__global__ __launch_bounds__(256) void k_gemm1(const float* __restrict__ x,
        const unsigned short* __restrict__ aggb, const unsigned short* __restrict__ BT,
        const float* __restrict__ ve, const int* __restrict__ cnt,
        float* __restrict__ h, float* __restrict__ stats) {
    __shared__ short As[64][40];     // stride 80B: 16B aligned, uniform banks
    __shared__ short Bs[128][40];
    __shared__ float red0[128], red1[128];
    __shared__ float ve_s[128];
    __shared__ int   deg_s[64];
    const int t = threadIdx.x;
    const int row0 = blockIdx.x * BM;
    if (t < 128) { ve_s[t] = ve[t]; red0[t] = 0.f; red1[t] = 0.f; }
    if (t < 64) deg_s[t] = cnt[min(row0 + t, N_NODES - 1)];
    const int w = t >> 6, l = t & 63;
    const int arow = w * 16 + (l & 15);
    const int koff = (l >> 4) * 8;
    f32x4 acc[8];
    #pragma unroll
    for (int ct = 0; ct < 8; ++ct) acc[ct] = (f32x4){0.f, 0.f, 0.f, 0.f};

    #pragma unroll 1
    for (int ch = 0; ch < 9; ++ch) {
        const int row = t >> 2, slot = t & 3;
        const int r = row0 + row;
        if (ch < 4) {   // A tile 64x32 from x (f32 -> bf16 staging)
            const int k0 = ch * 32;
            uint4 sv = make_uint4(0u, 0u, 0u, 0u);
            if (r < N_NODES) {
                const float* xp = x + (size_t)r * D_IN + k0 + slot * 8;
                float4 v0 = ld4(xp), v1 = ld4(xp + 4);
                sv.x = packbf2(v0.x, v0.y); sv.y = packbf2(v0.z, v0.w);
                sv.z = packbf2(v1.x, v1.y); sv.w = packbf2(v1.z, v1.w);
            }
            *reinterpret_cast<uint4*>(&As[row][slot * 8]) = sv;
        } else {        // A tile 64x32 from aggb (bf16)
            const int k0 = (ch - 4) * 32;
            uint4 v = make_uint4(0u, 0u, 0u, 0u);
            if (r < N_NODES)
                v = *reinterpret_cast<const uint4*>(aggb + (size_t)r * AGG_LD + k0 + slot * 8);
            *reinterpret_cast<uint4*>(&As[row][slot * 8]) = v;
        }
        const int kb = (ch < 4) ? ch * 32 : 128 + (ch - 4) * 32;
        #pragma unroll
        for (int i = 0; i < 2; ++i) {    // B tile 128x32 (K-major from BT)
            int qq = t + 256 * i;
            int brow = qq >> 2, bslot = qq & 3;
            *reinterpret_cast<uint4*>(&Bs[brow][bslot * 8]) =
                *reinterpret_cast<const uint4*>(BT + brow * 288 + kb + bslot * 8);
        }
        __syncthreads();
        bf16x8 af = *reinterpret_cast<const bf16x8*>(&As[arow][koff]);
        #pragma unroll
        for (int ct = 0; ct < 8; ++ct) {
            bf16x8 bfv = *reinterpret_cast<const bf16x8*>(&Bs[ct * 16 + (l & 15)][koff]);
            acc[ct] = __builtin_amdgcn_mfma_f32_16x16x32_bf16(af, bfv, acc[ct], 0, 0, 0);
        }
        __syncthreads();
    }

    #pragma unroll
    for (int ct = 0; ct < 8; ++ct) {
        const int col = ct * 16 + (l & 15);
        float cs0 = 0.f, cs1 = 0.f;
        #pragma unroll
        for (int i = 0; i < 4; ++i) {
            int lr = w * 16 + (l >> 4) * 4 + i;
            int r = row0 + lr;
            float dv = (float)deg_s[lr];
            float v = acc[ct][i] + dv * ve_s[col];
            if (r < N_NODES) { h[(size_t)r * 128 + col] = v; cs0 += v; cs1 += v * v; }
        }
        cs0 += __shfl_xor(cs0, 16); cs0 += __shfl_xor(cs0, 32);
        cs1 += __shfl_xor(cs1, 16); cs1 += __shfl_xor(cs1, 32);
        if (l < 16) { atomicAdd(&red0[col], cs0); atomicAdd(&red1[col], cs1); }
    }
    __syncthreads();
    if (t < 128) {
        unsafeAtomicAdd(stats + t,       red0[t]);
        unsafeAtomicAdd(stats + 128 + t, red1[t]);
    }
}

// MFMA GEMM2 (BN affine computed per-block from stats): out = GELU(a*h+b) @ W2 + b2
// h lives in d_out (in-place safe: block reads only its own rows)
__global__ __launch_bounds__(256) void k_gemm2(const float* __restrict__ h,
        const float* __restrict__ stats, const float* __restrict__ gamma,
        const float* __restrict__ beta, const unsigned short* __restrict__ W2T,
        const float* __restrict__ b2, float* __restrict__ out) {
    __shared__ short As[64][136];    // full K=128 staged once; stride 272B
    __shared__ short Bs[128][40];
    __shared__ float sa[128], sb[128], sc[128];
    const int t = threadIdx.x;
    const int row0 = blockIdx.x * BM;
    if (t < 128) {   // inline BN params
        float mu  = stats[t] * (1.0f / N_NODES);
        float var = stats[128 + t] * (1.0f / N_NODES) - mu * mu;
        float av  = gamma[t] * rsqrtf(var + 1e-5f);
        sa[t] = av;
        sb[t] = beta[t] - mu * av;
        sc[t] = b2[t];
    }
    __syncthreads();
    {   // stage A: affine + GELU -> bf16 (cvt_pk pairs)
        int row = t >> 2, q = t & 3;
        int r = row0 + row;
        #pragma unroll
        for (int i = 0; i < 8; ++i) {
            int c = q * 32 + i * 4;
            float4 v = (r < N_NODES) ? ld4(h + (size_t)r * 128 + c) : make_float4(0.f, 0.f, 0.f, 0.f);
            uint2 pw;
            pw.x = packbf2(gelu_exact(fmaf(sa[c],     v.x, sb[c])),
                           gelu_exact(fmaf(sa[c + 1], v.y, sb[c + 1])));
            pw.y = packbf2(gelu_exact(fmaf(sa[c + 2], v.z, sb[c + 2])),
                           gelu_exact(fmaf(sa[c + 3], v.w, sb[c + 3])));
            *reinterpret_cast<uint2*>(&As[row][c]) = pw;
        }
    }
    const int w = t >> 6, l = t & 63;
    const int arow = w * 16 + (l & 15);
    const int koff = (l >> 4) * 8;
    f32x4 acc[8];
    #pragma unroll
    for (int ct = 0; ct < 8; ++ct) acc[ct] = (f32x4){0.f, 0.f, 0.f, 0.f};

    #pragma unroll 1
    for (int ks = 0; ks < 4; ++ks) {
        #pragma unroll
        for (int i = 0; i < 2; ++i) {    // B tile 128x32 from W2T
            int qq = t + 256 * i;
            int row = qq >> 2, slot = qq & 3;
            *reinterpret_cast<uint4*>(&Bs[row][slot * 8]) =
                *reinterpret_cast<const uint4*>(W2T + row * 128 + ks * 32 + slot * 8);
        }
        __syncthreads();
        bf16x8 af = *reinterpret_cast<const bf16x8*>(&As[arow][ks * 32 + koff]);
        #pragma unroll
        for (int ct = 0; ct < 8; ++ct) {
            bf16x8 bfv = *reinterpret_cast<const bf16x8*>(&Bs[ct * 16 + (l & 15)][koff]);
            acc[ct] = __builtin_amdgcn_mfma_f32_16x16x32_bf16(af, bfv, acc[ct], 0, 0, 0);
        }
        __syncthreads();
    }
    #pragma unroll
    for (int ct = 0; ct < 8; ++ct) {
        const int col = ct * 16 + (l & 15);
        #pragma unroll
        for (int i = 0; i < 4; ++i) {
            int r = row0 + w * 16 + (l >> 4) * 4 + i;
            if (r < N_NODES) out[(size_t)r * 128 + col] = acc[ct][i] + sc[col];
        }
    }
}

extern "C" void kernel_launch(void* const* d_in, const int* in_sizes, int n_in,
                              void* d_out, int out_size, void* d_ws, size_t ws_size,
                              hipStream_t stream) {
    const float* x     = (const float*)d_in[0];
    const int*   eidx  = (const int*)d_in[1];
    const float* ef    = (const float*)d_in[2];
    const float* eW1   = (const float*)d_in[3];
    const float* eb1   = (const float*)d_in[4];
    const float* eW2   = (const float*)d_in[5];
    const float* eb2   = (const float*)d_in[6];
    const float* egoW  = (const float*)d_in[7];
    const float* eps   = (const float*)d_in[8];
    const float* W1    = (const float*)d_in[9];
    // d_in[10] = b1: cancels in BatchNorm (uniform shift), intentionally unused
    const float* gamma = (const float*)d_in[11];
    const float* beta  = (const float*)d_in[12];
    const float* W2    = (const float*)d_in[13];
    const float* b2    = (const float*)d_in[14];
    float* out = (float*)d_out;

    char* ws = (char*)d_ws;
    unsigned short* aggb = (unsigned short*)ws;              // N*144*2 + 128 pad = 14,400,128
    float* stats  = (float*)(ws + 14400128);                 // 1 KB   -> 14,401,152
    unsigned short* BT  = (unsigned short*)(ws + 14401152);  // 73,728 -> 14,474,880
    unsigned short* W2T = (unsigned short*)(ws + 14474880);  // 32,768 -> 14,507,648
    float* ve     = (float*)(ws + 14507648);                 // 512 B  -> 14,508,160
    int*   cnt    = (int*)(ws + 14508160);                   // 200,000 -> pad 14,708,864
    int*   bucket = (int*)(ws + 14708864);                   // N*48*4 = 9,600,000 -> 24,308,864
    unsigned short* gbuf = (unsigned short*)d_out;           // E*16 bf16 = 25.6 MB, dead before gemm1
    float* h      = out;                                     // h staged in d_out after k_agg

    k_zero<<<dim3(50), dim3(256), 0, stream>>>(cnt, stats);
    k_edge<<<dim3(EDGE_BLKS + 130), dim3(256), 0, stream>>>(x, eidx, ef, eW1, eb1,
                                                            egoW, W1, eps, eW2, eb2, W2,
                                                            cnt, bucket, gbuf, BT, W2T, ve);
    k_agg<<<dim3(N_NODES / 4), dim3(256), 0, stream>>>(x, eidx, cnt, bucket, gbuf, aggb);
    k_gemm1<<<dim3((N_NODES + BM - 1) / BM), dim3(256), 0, stream>>>(x, aggb, BT, ve,
                                                                     cnt, h, stats);
    k_gemm2<<<dim3((N_NODES + BM - 1) / BM), dim3(256), 0, stream>>>(h, stats, gamma, beta,
                                                                     W2T, b2, out);
}

// Round 15
// 169.234 us; speedup vs baseline: 1.1539x; 1.1539x over previous
//
#include <hip/hip_runtime.h>
#include <hip/hip_bf16.h>

#define N_NODES 50000
#define E_EDGES 800000
#define D_IN    128
#define ED_IN   32
#define H_HID   16
#define D_CAT   144
#define AGG_LD  144   // aggb row stride; gemm1 overreads 16 into next row, killed by BT zero cols
#define BCAP    48    // bucket capacity per node (P(deg>=48) ~ 5e-5; clamped)
#define BM      64    // rows per block in MFMA GEMM kernels
#define EDGE_BLKS (E_EDGES / 256)   // 3125

typedef __attribute__((ext_vector_type(8))) short bf16x8;   // 8 bf16 = 4 VGPRs
typedef __attribute__((ext_vector_type(4))) float f32x4;

__device__ __forceinline__ float gelu_exact(float v) {
    return 0.5f * v * (1.0f + erff(v * 0.70710678118654752f));
}
__device__ __forceinline__ float4 ld4(const float* p) { return *reinterpret_cast<const float4*>(p); }
__device__ __forceinline__ unsigned short f2bf(float f) {   // RNE bf16 (cold paths only)
    unsigned u = __float_as_uint(f);
    return (unsigned short)((u + 0x7FFFu + ((u >> 16) & 1u)) >> 16);
}
__device__ __forceinline__ float bflo(unsigned u) { return __uint_as_float(u << 16); }
__device__ __forceinline__ float bfhi(unsigned u) { return __uint_as_float(u & 0xffff0000u); }
// hot-path pair conversion -> v_cvt_pk_bf16_f32 (RNE)
__device__ __forceinline__ unsigned packbf2(float lo, float hi) {
    __hip_bfloat162 h = __float22bfloat162_rn(make_float2(lo, hi));
    return *reinterpret_cast<unsigned*>(&h);
}

// zero cnt (12500 int4) + stats (256 f32)
__global__ __launch_bounds__(256) void k_zero(int* __restrict__ cnt, float* __restrict__ stats) {
    int i = blockIdx.x * 256 + threadIdx.x;
    if (i < 12500) *reinterpret_cast<int4*>(cnt + i * 4) = make_int4(0, 0, 0, 0);
    if (blockIdx.x == 49 && threadIdx.x < 64)
        *reinterpret_cast<float4*>(stats + threadIdx.x * 4) = make_float4(0.f, 0.f, 0.f, 0.f);
}

// Fused edge kernel + weight-prep tail blocks.
// blocks 0..3124 (edge): (1) cast x->xb bf16 (1 uint4/thread);
//                        (2) placement: atomic on cnt[dst], 4B bucket store;
//                        (3) g = gelu(ef@eW1+eb1) via MFMA -> gbuf[e] coalesced.
// blocks 3125..3252: BT cols 0:128 = M = (1+eps)*egoW@W1   (d = b-3125)
// block  3253:       BT cols 128:256 = W1[0:128]; 256:272 = W1e; 272:288 = 0; ve
// block  3254:       W2T
__global__ __launch_bounds__(256) void k_edge(const float* __restrict__ x,
        uint4* __restrict__ xb, const int* __restrict__ eidx,
        const float* __restrict__ ef, const float* __restrict__ eW1,
        const float* __restrict__ eb1,
        const float* __restrict__ egoW, const float* __restrict__ W1,
        const float* __restrict__ eps, const float* __restrict__ eW2,
        const float* __restrict__ eb2, const float* __restrict__ W2,
        int* __restrict__ cnt, int* __restrict__ bucket,
        unsigned short* __restrict__ gbuf, unsigned short* __restrict__ BT,
        unsigned short* __restrict__ W2T, float* __restrict__ ve) {
    const int b = blockIdx.x, t = threadIdx.x;
    if (b >= EDGE_BLKS) {                    // ---- prep tail blocks ----
        if (t >= 128) return;
        const int c = t;
        const int d = b - EDGE_BLKS;
        if (d < 128) {
            float acc = 0.f;
            for (int j = 0; j < D_CAT; ++j)
                acc = fmaf(egoW[d * D_CAT + j], W1[j * 128 + c], acc);
            BT[c * 288 + d] = f2bf((1.0f + eps[0]) * acc);
        } else if (d == 128) {
            for (int j = 0; j < 128; ++j)
                BT[c * 288 + 128 + j] = f2bf(W1[j * 128 + c]);
            #pragma unroll
            for (int j = 0; j < H_HID; ++j) {
                float s = 0.f;
                #pragma unroll
                for (int k = 0; k < H_HID; ++k)
                    s = fmaf(eW2[j * H_HID + k], W1[(D_IN + k) * 128 + c], s);
                BT[c * 288 + 256 + j] = f2bf(s);
            }
            #pragma unroll
            for (int j = 272; j < 288; ++j) BT[c * 288 + j] = 0;
            float s = 0.f;
            #pragma unroll
            for (int k = 0; k < H_HID; ++k)
                s = fmaf(eb2[k], W1[(D_IN + k) * 128 + c], s);
            ve[c] = s;
        } else {
            for (int k = 0; k < 128; ++k)
                W2T[c * 128 + k] = f2bf(W2[k * 128 + c]);
        }
        return;
    }
    // ---- edge blocks ----
    const int e0 = b * 256;
    const int i = e0 + t;
    const int w = t >> 6, l = t & 63, q = l >> 4, c = l & 15;
    const int eb = e0 + w * 64;

    // issue phase: all independent global loads
    float4 cx0 = ld4(x + (size_t)i * 8);            // cast inputs
    float4 cx1 = ld4(x + (size_t)i * 8 + 4);
    int dst = eidx[E_EDGES + i];                    // placement input
    float4 ef0[4], ef1[4];                          // MFMA B-operands, 4 steps
    #pragma unroll
    for (int m = 0; m < 4; ++m) {
        const float* ep = ef + (size_t)(eb + m * 16 + c) * ED_IN + q * 8;
        ef0[m] = ld4(ep);
        ef1[m] = ld4(ep + 4);
    }
    float wv[8];
    #pragma unroll
    for (int j = 0; j < 8; ++j) wv[j] = eW1[(q * 8 + j) * 16 + c];
    union { uint4 u; bf16x8 v; } afc;
    afc.u.x = packbf2(wv[0], wv[1]); afc.u.y = packbf2(wv[2], wv[3]);
    afc.u.z = packbf2(wv[4], wv[5]); afc.u.w = packbf2(wv[6], wv[7]);
    const bf16x8 af = afc.v;                        // A[row=c][k=q*8+j]
    float bias[4];
    #pragma unroll
    for (int j = 0; j < 4; ++j) bias[j] = eb1[q * 4 + j];

    {   // (1) cast store
        uint4 o;
        o.x = packbf2(cx0.x, cx0.y); o.y = packbf2(cx0.z, cx0.w);
        o.z = packbf2(cx1.x, cx1.y); o.w = packbf2(cx1.z, cx1.w);
        xb[i] = o;
    }
    {   // (2) placement
        int pos = atomicAdd(&cnt[dst], 1);
        if (pos < BCAP) bucket[dst * BCAP + pos] = i;
    }
    // (3) g-MFMA: 4 x mfma_16x16x32, coalesced gbuf writes
    #pragma unroll
    for (int m = 0; m < 4; ++m) {
        const int em = eb + m * 16 + c;
        union { uint4 u; bf16x8 v; } bc;
        bc.u.x = packbf2(ef0[m].x, ef0[m].y); bc.u.y = packbf2(ef0[m].z, ef0[m].w);
        bc.u.z = packbf2(ef1[m].x, ef1[m].y); bc.u.w = packbf2(ef1[m].z, ef1[m].w);
        f32x4 acc = (f32x4){0.f, 0.f, 0.f, 0.f};
        acc = __builtin_amdgcn_mfma_f32_16x16x32_bf16(af, bc.v, acc, 0, 0, 0);
        uint2 o;
        o.x = packbf2(gelu_exact(acc[0] + bias[0]), gelu_exact(acc[1] + bias[1]));
        o.y = packbf2(gelu_exact(acc[2] + bias[2]), gelu_exact(acc[3] + bias[3]));
        *reinterpret_cast<uint2*>(gbuf + (size_t)em * 16 + q * 4) = o;
    }
}

// Bucket aggregation -> aggb rows [x(128) | g(16)] bf16, stride 144.
// Gathers bf16 xb rows (16B/lane, cache-resident); g bf16 from gbuf.
__global__ __launch_bounds__(256) void k_agg(const unsigned short* __restrict__ xb,
        const int* __restrict__ eidx, const int* __restrict__ cnt,
        const int* __restrict__ bucket, const unsigned short* __restrict__ gbuf,
        unsigned short* __restrict__ aggb) {
    const int wave = threadIdx.x >> 6, lane = threadIdx.x & 63;
    const int q = lane >> 4, ql = lane & 15;
    const int n = blockIdx.x * 4 + wave;
    const int m = min(cnt[n], BCAP);
    int ev = (lane < BCAP) ? bucket[n * BCAP + lane] : 0;
    int sv = (lane < m) ? eidx[ev] : 0;             // per-lane src, independent loads
    float a[8], ae[8];
    #pragma unroll
    for (int i = 0; i < 8; ++i) { a[i] = 0.f; ae[i] = 0.f; }
    const int ng = (m + 3) >> 2;
    #pragma unroll 4
    for (int j = 0; j < ng; ++j) {
        const int eo = 4 * j + q;
        const int s  = __shfl(sv, eo);
        const int ge = __shfl(ev, eo);
        if (eo < m) {
            uint4 v = *reinterpret_cast<const uint4*>(xb + (size_t)s * D_IN + ql * 8);
            a[0] += bflo(v.x); a[1] += bfhi(v.x);
            a[2] += bflo(v.y); a[3] += bfhi(v.y);
            a[4] += bflo(v.z); a[5] += bfhi(v.z);
            a[6] += bflo(v.w); a[7] += bfhi(v.w);
            if (ql < 2) {
                uint4 e = *reinterpret_cast<const uint4*>(gbuf + (size_t)ge * 16 + ql * 8);
                ae[0] += bflo(e.x); ae[1] += bfhi(e.x);
                ae[2] += bflo(e.y); ae[3] += bfhi(e.y);
                ae[4] += bflo(e.z); ae[5] += bfhi(e.z);
                ae[6] += bflo(e.w); ae[7] += bfhi(e.w);
            }
        }
    }
    #pragma unroll
    for (int i = 0; i < 8; ++i) {
        a[i]  += __shfl_xor(a[i], 16);  a[i]  += __shfl_xor(a[i], 32);
        ae[i] += __shfl_xor(ae[i], 16); ae[i] += __shfl_xor(ae[i], 32);
    }
    if (q == 0) {
        unsigned short* ar = aggb + (size_t)n * AGG_LD;
        uint4 o;
        o.x = packbf2(a[0], a[1]); o.y = packbf2(a[2], a[3]);
        o.z = packbf2(a[4], a[5]); o.w = packbf2(a[6], a[7]);
        *reinterpret_cast<uint4*>(ar + ql * 8) = o;
        if (ql < 2) {
            uint4 oe;
            oe.x = packbf2(ae[0], ae[1]); oe.y = packbf2(ae[2], ae[3]);
            oe.z = packbf2(ae[4], ae[5]); oe.w = packbf2(ae[6], ae[7]);
            *reinterpret_cast<uint4*>(ar + D_IN + ql * 8) = oe;
        }
    }
}

// MFMA GEMM1: h[N,128] = [xb | aggb] @ BT^T + deg*ve ; col stats
// A-overread past aggb row end (16 elems of next row) hits BT zero cols 272:288 -> no-op.
__global__ __launch_bounds__(256) void k_gemm1(const unsigned short* __restrict__ xb,
        const unsigned short* __restrict__ aggb, const unsigned short* __restrict__ BT,
        const float* __restrict__ ve, const int* __restrict__ cnt,
        float* __restrict__ h, float* __restrict__ stats) {
    __shared__ short As[64][40];     // stride 80B: 16B aligned, uniform banks
    __shared__ short Bs[128][40];
    __shared__ float red0[128], red1[128];
    __shared__ float ve_s[128];
    __shared__ int   deg_s[64];
    const int t = threadIdx.x;
    const int row0 = blockIdx.x * BM;
    if (t < 128) { ve_s[t] = ve[t]; red0[t] = 0.f; red1[t] = 0.f; }
    if (t < 64) deg_s[t] = cnt[min(row0 + t, N_NODES - 1)];
    const int w = t >> 6, l = t & 63;
    const int arow = w * 16 + (l & 15);
    const int koff = (l >> 4) * 8;
    f32x4 acc[8];
    #pragma unroll
    for (int ct = 0; ct < 8; ++ct) acc[ct] = (f32x4){0.f, 0.f, 0.f, 0.f};

    #pragma unroll 1
    for (int ch = 0; ch < 9; ++ch) {
        const unsigned short* Ab; int lda, k0, kb;
        if (ch < 4) { Ab = xb;   lda = D_IN;   k0 = ch * 32;       kb = ch * 32; }
        else        { Ab = aggb; lda = AGG_LD; k0 = (ch - 4) * 32; kb = 128 + (ch - 4) * 32; }
        {   // A tile 64x32
            int row = t >> 2, slot = t & 3;
            int r = row0 + row;
            uint4 v = make_uint4(0u, 0u, 0u, 0u);
            if (r < N_NODES) v = *reinterpret_cast<const uint4*>(Ab + (size_t)r * lda + k0 + slot * 8);
            *reinterpret_cast<uint4*>(&As[row][slot * 8]) = v;
        }
        #pragma unroll
        for (int i = 0; i < 2; ++i) {    // B tile 128x32 (K-major from BT)
            int qq = t + 256 * i;
            int row = qq >> 2, slot = qq & 3;
            *reinterpret_cast<uint4*>(&Bs[row][slot * 8]) =
                *reinterpret_cast<const uint4*>(BT + row * 288 + kb + slot * 8);
        }
        __syncthreads();
        bf16x8 af = *reinterpret_cast<const bf16x8*>(&As[arow][koff]);
        #pragma unroll
        for (int ct = 0; ct < 8; ++ct) {
            bf16x8 bfv = *reinterpret_cast<const bf16x8*>(&Bs[ct * 16 + (l & 15)][koff]);
            acc[ct] = __builtin_amdgcn_mfma_f32_16x16x32_bf16(af, bfv, acc[ct], 0, 0, 0);
        }
        __syncthreads();
    }

    #pragma unroll
    for (int ct = 0; ct < 8; ++ct) {
        const int col = ct * 16 + (l & 15);
        float cs0 = 0.f, cs1 = 0.f;
        #pragma unroll
        for (int i = 0; i < 4; ++i) {
            int lr = w * 16 + (l >> 4) * 4 + i;
            int r = row0 + lr;
            float dv = (float)deg_s[lr];
            float v = acc[ct][i] + dv * ve_s[col];
            if (r < N_NODES) { h[(size_t)r * 128 + col] = v; cs0 += v; cs1 += v * v; }
        }
        cs0 += __shfl_xor(cs0, 16); cs0 += __shfl_xor(cs0, 32);
        cs1 += __shfl_xor(cs1, 16); cs1 += __shfl_xor(cs1, 32);
        if (l < 16) { atomicAdd(&red0[col], cs0); atomicAdd(&red1[col], cs1); }
    }
    __syncthreads();
    if (t < 128) {
        unsafeAtomicAdd(stats + t,       red0[t]);
        unsafeAtomicAdd(stats + 128 + t, red1[t]);
    }
}

// MFMA GEMM2 (BN affine computed per-block from stats): out = GELU(a*h+b) @ W2 + b2
// h lives in d_out (in-place safe: block reads only its own rows)
__global__ __launch_bounds__(256) void k_gemm2(const float* __restrict__ h,
        const float* __restrict__ stats, const float* __restrict__ gamma,
        const float* __restrict__ beta, const unsigned short* __restrict__ W2T,
        const float* __restrict__ b2, float* __restrict__ out) {
    __shared__ short As[64][136];    // full K=128 staged once; stride 272B
    __shared__ short Bs[128][40];
    __shared__ float sa[128], sb[128], sc[128];
    const int t = threadIdx.x;
    const int row0 = blockIdx.x * BM;
    if (t < 128) {   // inline BN params
        float mu  = stats[t] * (1.0f / N_NODES);
        float var = stats[128 + t] * (1.0f / N_NODES) - mu * mu;
        float av  = gamma[t] * rsqrtf(var + 1e-5f);
        sa[t] = av;
        sb[t] = beta[t] - mu * av;
        sc[t] = b2[t];
    }
    __syncthreads();
    {   // stage A: affine + GELU -> bf16 (cvt_pk pairs)
        int row = t >> 2, q = t & 3;
        int r = row0 + row;
        #pragma unroll
        for (int i = 0; i < 8; ++i) {
            int c = q * 32 + i * 4;
            float4 v = (r < N_NODES) ? ld4(h + (size_t)r * 128 + c) : make_float4(0.f, 0.f, 0.f, 0.f);
            uint2 pw;
            pw.x = packbf2(gelu_exact(fmaf(sa[c],     v.x, sb[c])),
                           gelu_exact(fmaf(sa[c + 1], v.y, sb[c + 1])));
            pw.y = packbf2(gelu_exact(fmaf(sa[c + 2], v.z, sb[c + 2])),
                           gelu_exact(fmaf(sa[c + 3], v.w, sb[c + 3])));
            *reinterpret_cast<uint2*>(&As[row][c]) = pw;
        }
    }
    const int w = t >> 6, l = t & 63;
    const int arow = w * 16 + (l & 15);
    const int koff = (l >> 4) * 8;
    f32x4 acc[8];
    #pragma unroll
    for (int ct = 0; ct < 8; ++ct) acc[ct] = (f32x4){0.f, 0.f, 0.f, 0.f};

    #pragma unroll 1
    for (int ks = 0; ks < 4; ++ks) {
        #pragma unroll
        for (int i = 0; i < 2; ++i) {    // B tile 128x32 from W2T
            int qq = t + 256 * i;
            int row = qq >> 2, slot = qq & 3;
            *reinterpret_cast<uint4*>(&Bs[row][slot * 8]) =
                *reinterpret_cast<const uint4*>(W2T + row * 128 + ks * 32 + slot * 8);
        }
        __syncthreads();
        bf16x8 af = *reinterpret_cast<const bf16x8*>(&As[arow][ks * 32 + koff]);
        #pragma unroll
        for (int ct = 0; ct < 8; ++ct) {
            bf16x8 bfv = *reinterpret_cast<const bf16x8*>(&Bs[ct * 16 + (l & 15)][koff]);
            acc[ct] = __builtin_amdgcn_mfma_f32_16x16x32_bf16(af, bfv, acc[ct], 0, 0, 0);
        }
        __syncthreads();
    }
    #pragma unroll
    for (int ct = 0; ct < 8; ++ct) {
        const int col = ct * 16 + (l & 15);
        #pragma unroll
        for (int i = 0; i < 4; ++i) {
            int r = row0 + w * 16 + (l >> 4) * 4 + i;
            if (r < N_NODES) out[(size_t)r * 128 + col] = acc[ct][i] + sc[col];
        }
    }
}

extern "C" void kernel_launch(void* const* d_in, const int* in_sizes, int n_in,
                              void* d_out, int out_size, void* d_ws, size_t ws_size,
                              hipStream_t stream) {
    const float* x     = (const float*)d_in[0];
    const int*   eidx  = (const int*)d_in[1];
    const float* ef    = (const float*)d_in[2];
    const float* eW1   = (const float*)d_in[3];
    const float* eb1   = (const float*)d_in[4];
    const float* eW2   = (const float*)d_in[5];
    const float* eb2   = (const float*)d_in[6];
    const float* egoW  = (const float*)d_in[7];
    const float* eps   = (const float*)d_in[8];
    const float* W1    = (const float*)d_in[9];
    // d_in[10] = b1: cancels in BatchNorm (uniform shift), intentionally unused
    const float* gamma = (const float*)d_in[11];
    const float* beta  = (const float*)d_in[12];
    const float* W2    = (const float*)d_in[13];
    const float* b2    = (const float*)d_in[14];
    float* out = (float*)d_out;

    char* ws = (char*)d_ws;
    unsigned short* aggb = (unsigned short*)ws;              // N*144*2 + 128 pad = 14,400,128
    unsigned short* xb   = (unsigned short*)(ws + 14400128); // 12,800,000 -> 27,200,128
    float* stats  = (float*)(ws + 27200128);                 // 1 KB   -> 27,201,152
    unsigned short* BT  = (unsigned short*)(ws + 27201152);  // 73,728 -> 27,274,880
    unsigned short* W2T = (unsigned short*)(ws + 27274880);  // 32,768 -> 27,307,648
    float* ve     = (float*)(ws + 27307648);                 // 512 B  -> 27,308,160
    int*   cnt    = (int*)(ws + 27308160);                   // 200,000 -> pad 27,508,864
    int*   bucket = (int*)(ws + 27508864);                   // N*48*4 = 9,600,000 -> 37,108,864
    unsigned short* gbuf = (unsigned short*)d_out;           // E*16 bf16 = 25.6 MB, dead before gemm1
    float* h      = out;                                     // h staged in d_out after k_agg

    k_zero<<<dim3(50), dim3(256), 0, stream>>>(cnt, stats);
    k_edge<<<dim3(EDGE_BLKS + 130), dim3(256), 0, stream>>>(x, (uint4*)xb, eidx, ef, eW1, eb1,
                                                            egoW, W1, eps, eW2, eb2, W2,
                                                            cnt, bucket, gbuf, BT, W2T, ve);
    k_agg<<<dim3(N_NODES / 4), dim3(256), 0, stream>>>(xb, eidx, cnt, bucket, gbuf, aggb);
    k_gemm1<<<dim3((N_NODES + BM - 1) / BM), dim3(256), 0, stream>>>(xb, aggb, BT, ve,
                                                                     cnt, h, stats);
    k_gemm2<<<dim3((N_NODES + BM - 1) / BM), dim3(256), 0, stream>>>(h, stats, gamma, beta,
                                                                     W2T, b2, out);
}